// Round 4
// baseline (3398.446 us; speedup 1.0000x reference)
//
#include <hip/hip_runtime.h>
#include <hip/hip_bf16.h>
#include <cstdint>

typedef float floatx4 __attribute__((ext_vector_type(4)));

#define NBLK 256          // binning writer blocks
#define ROWS 8            // entities per bucket
#define CAP  48           // per-(bucket,block) record capacity (lambda=7.8, P(>48)~e-49)

// ---------------------------------------------------------------------------
// Kernel 0: rwbP[k][l] = pack_f16(RWB[k][l], RWB[k][l+64]),  RWB = rel@W^T + b
// Packed so the agg gather is one dword/lane covering cols (l, l+64).
// ---------------------------------------------------------------------------
__global__ void rwb_kernel(const float* __restrict__ rel, const float* __restrict__ W,
                           const float* __restrict__ b, unsigned* __restrict__ rwbP,
                           int R) {
    const int k = blockIdx.x;
    const int n = threadIdx.x;
    __shared__ float tmp[128];
    float acc = 0.f;
    if (k < R) {
        __shared__ float relk[128];
        relk[n] = rel[(size_t)k * 128 + n];
        __syncthreads();
        const float4* w4 = reinterpret_cast<const float4*>(W + (size_t)n * 128);
        const float4* r4 = reinterpret_cast<const float4*>(relk);
#pragma unroll
        for (int i = 0; i < 32; ++i) {
            float4 a = r4[i], w = w4[i];
            acc += a.x * w.x + a.y * w.y + a.z * w.z + a.w * w.w;
        }
        acc += b[n];
    }
    tmp[n] = acc;
    __syncthreads();
    if (n < 64) {
        const _Float16 lo = (_Float16)tmp[n];
        const _Float16 hi = (_Float16)tmp[n + 64];
        unsigned pk = (unsigned)__builtin_bit_cast(unsigned short, lo) |
                      ((unsigned)__builtin_bit_cast(unsigned short, hi) << 16);
        rwbP[(size_t)k * 64 + n] = pk;
    }
}

// ---------------------------------------------------------------------------
// Kernel 1: bin the 4M fact endpoints into fixed-capacity per-(bucket,block)
// regions. Record = r(11) | row(3) | val_fixed18(18). LDS cursors only; no
// global atomics, no hist/scan passes. Epilogue zero-pads each segment to a
// multiple of 4 and writes the rounded count.
// ---------------------------------------------------------------------------
__global__ void binscatter_kernel(const int* __restrict__ heads, const int* __restrict__ tails,
                                  const int* __restrict__ rels, const float* __restrict__ val,
                                  unsigned* __restrict__ fact_buf, int* __restrict__ cnt,
                                  int E, int NBUCK, int chunk) {
    __shared__ int cur[4096];
    const int t = threadIdx.x;
    for (int i = t; i < NBUCK; i += blockDim.x) cur[i] = 0;
    __syncthreads();
    const int ITEMS = 2 * E;
    const int start = blockIdx.x * chunk;
    const int end = min(start + chunk, ITEMS);
    for (int i = start + t; i < end; i += blockDim.x) {
        const int e = (i < E) ? i : i - E;
        const int v = (i < E) ? tails[i] : heads[e];
        const int r = rels[e];
        float w = val[e];
        w = fminf(fmaxf(w, 0.f), 1.f);
        unsigned q = (unsigned)(w * 262143.f + 0.5f);
        if (q > 262143u) q = 262143u;
        const int bkt = v >> 3;
        const unsigned rec = (unsigned)r | ((unsigned)(v & 7) << 11) | (q << 14);
        const int pos = atomicAdd(&cur[bkt], 1);
        if (pos < CAP)
            fact_buf[((size_t)bkt * NBLK + blockIdx.x) * CAP + pos] = rec;
    }
    __syncthreads();
    for (int bkt = t; bkt < NBUCK; bkt += blockDim.x) {
        int c = min(cur[bkt], CAP);
        unsigned* seg = fact_buf + ((size_t)bkt * NBLK + blockIdx.x) * CAP;
        while (c & 3) { seg[c] = 0u; ++c; }   // zero-record: r=0,row=0,val=0
        cnt[(size_t)bkt * NBLK + blockIdx.x] = c;
    }
}

// ---------------------------------------------------------------------------
// Kernel 2: per-bucket aggregate. For each record, the whole wave gathers
// RWB[r] (1 dword/lane = cols l, l+64) and ds_add_f32 into accum[8][128].
// Bank pattern: both adds hit bank l%32 -> 2 lanes/bank = conflict-free.
// 4 KB LDS -> ~8 blocks/CU for latency hiding. Then relu + contiguous store.
// ---------------------------------------------------------------------------
__global__ __launch_bounds__(256) void agg_kernel(
    const unsigned* __restrict__ fact_buf, const int* __restrict__ cnt,
    const unsigned* __restrict__ rwbP, float* __restrict__ out, int NUMENT) {
    __shared__ float accum[ROWS * 128];   // 4 KB
    __shared__ int cnts[NBLK];
    const int b = blockIdx.x;
    const int t = threadIdx.x;
    accum[t] = 0.f; accum[t + 256] = 0.f;
    accum[t + 512] = 0.f; accum[t + 768] = 0.f;
    cnts[t] = cnt[(size_t)b * NBLK + t];
    __syncthreads();

    const int w = t >> 6, lane = t & 63;
    const unsigned* fb = fact_buf + (size_t)b * NBLK * CAP;
    for (int s = 0; s < NBLK / 4; ++s) {
        const int seg = w * (NBLK / 4) + s;
        const int n = cnts[seg];                    // multiple of 4
        const unsigned* base = fb + (size_t)seg * CAP;
        for (int j = 0; j < n; j += 4) {
            const uint4 g = *reinterpret_cast<const uint4*>(base + j);  // broadcast
#pragma unroll
            for (int q = 0; q < 4; ++q) {
                const unsigned rec = (q == 0) ? g.x : (q == 1) ? g.y : (q == 2) ? g.z : g.w;
                const int r = (int)(rec & 2047u);
                const int row = (int)((rec >> 11) & 7u);
                const float v = (float)(rec >> 14) * (1.f / 262143.f);
                const unsigned pk = rwbP[(size_t)r * 64 + lane];
                const float lo = (float)__builtin_bit_cast(_Float16, (unsigned short)(pk & 0xFFFFu));
                const float hi = (float)__builtin_bit_cast(_Float16, (unsigned short)(pk >> 16));
                atomicAdd(&accum[row * 128 + lane], lo * v);
                atomicAdd(&accum[row * 128 + 64 + lane], hi * v);
            }
        }
    }
    __syncthreads();

    const size_t obase = (size_t)b * (ROWS * 128);
    const size_t omax = (size_t)NUMENT * 128;
#pragma unroll
    for (int i = 0; i < 4; ++i) {
        const int idx = t + i * 256;
        if (obase + idx < omax) out[obase + idx] = fmaxf(accum[idx], 0.f);
    }
}

// ---------------------------------------------------------------------------
// Fallback path (only if assumptions violated): direct vector scatter.
// ---------------------------------------------------------------------------
__global__ void rwb_f32_kernel(const float* __restrict__ rel, const float* __restrict__ W,
                               const float* __restrict__ b, float* __restrict__ rwb, int R) {
    const int k = blockIdx.x;
    const int n = threadIdx.x;
    __shared__ float relk[128];
    relk[n] = rel[(size_t)k * 128 + n];
    __syncthreads();
    const float4* w4 = reinterpret_cast<const float4*>(W + (size_t)n * 128);
    const float4* r4 = reinterpret_cast<const float4*>(relk);
    float acc = 0.f;
#pragma unroll
    for (int i = 0; i < 32; ++i) {
        float4 a = r4[i], w = w4[i];
        acc += a.x * w.x + a.y * w.y + a.z * w.z + a.w * w.w;
    }
    rwb[(size_t)k * 128 + n] = acc + b[n];
}

__global__ void scatter_vec_kernel(const int* __restrict__ heads, const int* __restrict__ tails,
                                   const int* __restrict__ rels, const float* __restrict__ val,
                                   const float* __restrict__ rwb, float* __restrict__ out,
                                   long long nitems) {
    const long long i = (long long)blockIdx.x * blockDim.x + threadIdx.x;
    if (i >= nitems) return;
    const int e = (int)(i >> 5);
    const int c = (int)(i & 31) * 4;
    const float v = val[e];
    float4 rw = *reinterpret_cast<const float4*>(rwb + (size_t)rels[e] * 128 + c);
    float* pt = out + (size_t)tails[e] * 128 + c;
    float* ph = out + (size_t)heads[e] * 128 + c;
    unsafeAtomicAdd(pt + 0, v * rw.x); unsafeAtomicAdd(pt + 1, v * rw.y);
    unsafeAtomicAdd(pt + 2, v * rw.z); unsafeAtomicAdd(pt + 3, v * rw.w);
    unsafeAtomicAdd(ph + 0, v * rw.x); unsafeAtomicAdd(ph + 1, v * rw.y);
    unsafeAtomicAdd(ph + 2, v * rw.z); unsafeAtomicAdd(ph + 3, v * rw.w);
}

__global__ void relu_kernel(float* __restrict__ out, int n4) {
    const int i = blockIdx.x * blockDim.x + threadIdx.x;
    if (i >= n4) return;
    float4* p = reinterpret_cast<float4*>(out) + i;
    float4 v = *p;
    v.x = fmaxf(v.x, 0.f); v.y = fmaxf(v.y, 0.f);
    v.z = fmaxf(v.z, 0.f); v.w = fmaxf(v.w, 0.f);
    *p = v;
}

// ---------------------------------------------------------------------------
extern "C" void kernel_launch(void* const* d_in, const int* in_sizes, int n_in,
                              void* d_out, int out_size, void* d_ws, size_t ws_size,
                              hipStream_t stream) {
    // inputs: 0 local_entity [B*M], 1 heads [E], 2 tails [E], 3 rels [E],
    //         4 val [E], 5 rel_features [R*D], 6 W [D*D], 7 b [D]
    const int* heads = (const int*)d_in[1];
    const int* tails = (const int*)d_in[2];
    const int* rels  = (const int*)d_in[3];
    const float* val  = (const float*)d_in[4];
    const float* relf = (const float*)d_in[5];
    const float* W    = (const float*)d_in[6];
    const float* b    = (const float*)d_in[7];
    float* out = (float*)d_out;

    const int NUMENT = in_sizes[0];          // 16000
    const int E      = in_sizes[1];          // 2,000,000
    const int D      = in_sizes[7];          // 128
    const int R      = in_sizes[5] / D;      // 2000
    const int NBUCK  = (NUMENT + ROWS - 1) / ROWS;   // 2000
    const int ITEMS  = 2 * E;
    const int chunk  = (ITEMS + NBLK - 1) / NBLK;

    // workspace layout
    const size_t rwb_bytes  = (size_t)2048 * 64 * sizeof(unsigned);      // 512 KB
    const size_t cnt_off    = (rwb_bytes + 255) & ~(size_t)255;
    const size_t cnt_bytes  = (size_t)NBUCK * NBLK * sizeof(int);        // 2 MB
    const size_t fact_off   = (cnt_off + cnt_bytes + 255) & ~(size_t)255;
    const size_t fact_bytes = (size_t)NBUCK * NBLK * CAP * sizeof(unsigned); // 98.3 MB
    const size_t total      = fact_off + fact_bytes;

    const bool fast = (D == 128) && (R <= 2048) && (NBUCK <= 4096) &&
                      (ws_size >= total);

    if (fast) {
        unsigned* rwbP = (unsigned*)d_ws;
        int* cnt       = (int*)((char*)d_ws + cnt_off);
        unsigned* fbuf = (unsigned*)((char*)d_ws + fact_off);

        rwb_kernel<<<2048, 128, 0, stream>>>(relf, W, b, rwbP, R);
        binscatter_kernel<<<NBLK, 256, 0, stream>>>(heads, tails, rels, val,
                                                    fbuf, cnt, E, NBUCK, chunk);
        agg_kernel<<<NBUCK, 256, 0, stream>>>(fbuf, cnt, rwbP, out, NUMENT);
    } else {
        // fallback: accumulate directly into out
        float* rwb = (float*)d_ws;
        hipMemsetAsync(out, 0, (size_t)out_size * sizeof(float), stream);
        rwb_f32_kernel<<<R, 128, 0, stream>>>(relf, W, b, rwb, R);
        const long long items = (long long)E * 32;
        scatter_vec_kernel<<<(unsigned)((items + 255) / 256), 256, 0, stream>>>(
            heads, tails, rels, val, rwb, out, items);
        relu_kernel<<<(out_size / 4 + 255) / 256, 256, 0, stream>>>(out, out_size / 4);
    }
}

// Round 5
// 427.368 us; speedup vs baseline: 7.9520x; 7.9520x over previous
//
#include <hip/hip_runtime.h>
#include <hip/hip_bf16.h>
#include <cstdint>

typedef _Float16 half8 __attribute__((ext_vector_type(8)));
typedef float floatx4 __attribute__((ext_vector_type(4)));

#define KPC 2048
// HW_REG_XCC_ID (id=20, offset=0, size=4)  [measured: learn_hip m09]
#define XCC_GETREG ((3 << 11) | 20)

// ---------------------------------------------------------------------------
// Kernel 0: rwbT[n][k] = dot(rel_features[k,:], W[n,:]) + b[n]  (fp16, [128][KPC])
// k >= R rows are zero.
// ---------------------------------------------------------------------------
__global__ void rwb_kernel(const float* __restrict__ rel, const float* __restrict__ W,
                           const float* __restrict__ b, _Float16* __restrict__ rwbT,
                           int R) {
    const int k = blockIdx.x;
    const int n = threadIdx.x;
    __shared__ float relk[128];
    if (k < R) relk[n] = rel[(size_t)k * 128 + n];
    __syncthreads();
    float acc = 0.f;
    if (k < R) {
        const float4* w4 = reinterpret_cast<const float4*>(W + (size_t)n * 128);
        const float4* r4 = reinterpret_cast<const float4*>(relk);
#pragma unroll
        for (int i = 0; i < 32; ++i) {
            float4 a = r4[i], w = w4[i];
            acc += a.x * w.x + a.y * w.y + a.z * w.z + a.w * w.w;
        }
        acc += b[n];
    }
    rwbT[(size_t)n * KPC + k] = (_Float16)acc;
}

// ---------------------------------------------------------------------------
// Kernel 1: XCD-sliced scatter. Entity slice = v >> slice_shift (8 slices).
// Each block serves its own XCD's slice only; all atomics on a line come from
// one XCD, so workgroup-scope (L2-point) atomics are coherent. Chunk claiming
// via per-slice device counters covers every fact once per slice regardless
// of block->XCD distribution.
// ---------------------------------------------------------------------------
__global__ __launch_bounds__(256) void xcd_scatter_kernel(
    const int* __restrict__ heads, const int* __restrict__ tails,
    const int* __restrict__ rels, const float* __restrict__ val,
    float* __restrict__ S, int* __restrict__ counters,
    int E, int nchunk, int chunk, int slice_shift) {
    __shared__ int s_chunk;
    const int xcd = __builtin_amdgcn_s_getreg(XCC_GETREG) & 7;
    for (;;) {
        __syncthreads();
        if (threadIdx.x == 0) s_chunk = atomicAdd(&counters[xcd], 1);
        __syncthreads();
        const int c = s_chunk;
        if (c >= nchunk) break;
        const int base = c * chunk;
        const int end = min(base + chunk, E);
        for (int i = base + (int)threadIdx.x; i < end; i += 256) {
            const int tv = tails[i];
            const int hv = heads[i];
            const int r = rels[i];
            const float w = val[i];
            if ((tv >> slice_shift) == xcd)
                __hip_atomic_fetch_add(&S[(size_t)tv * KPC + r], w,
                                       __ATOMIC_RELAXED, __HIP_MEMORY_SCOPE_WORKGROUP);
            if ((hv >> slice_shift) == xcd)
                __hip_atomic_fetch_add(&S[(size_t)hv * KPC + r], w,
                                       __ATOMIC_RELAXED, __HIP_MEMORY_SCOPE_WORKGROUP);
        }
    }
}

// ---------------------------------------------------------------------------
// Kernel 2: LDS-free direct-fragment GEMM. One wave per 16 rows; no barriers.
// A-frag: lane l reads S[m0 + (l&15)][k0 + (l>>4)*8 ..+8) (fp32 -> f16 cvt).
// B-frag: rwbT[ni*16 + (l&15)][k0 + (l>>4)*8 ..+8) (L2-hot, 512 KB).
// M=16000 divisible by 16 -> no bounds checks.
// ---------------------------------------------------------------------------
__global__ __launch_bounds__(64) void gemm16_kernel(
    const float* __restrict__ S, const _Float16* __restrict__ rwbT,
    float* __restrict__ out) {
    const int l = threadIdx.x;
    const int quad = l >> 4;
    const int fr = l & 15;
    const int m0 = blockIdx.x * 16;

    const float* ap = S + (size_t)(m0 + fr) * KPC + quad * 8;
    const _Float16* bp = rwbT + (size_t)fr * KPC + quad * 8;

    floatx4 acc[8] = {};

#pragma unroll 2
    for (int k0 = 0; k0 < KPC; k0 += 32) {
        const float4 a0 = *reinterpret_cast<const float4*>(ap + k0);
        const float4 a1 = *reinterpret_cast<const float4*>(ap + k0 + 4);
        half8 af;
        af[0] = (_Float16)a0.x; af[1] = (_Float16)a0.y;
        af[2] = (_Float16)a0.z; af[3] = (_Float16)a0.w;
        af[4] = (_Float16)a1.x; af[5] = (_Float16)a1.y;
        af[6] = (_Float16)a1.z; af[7] = (_Float16)a1.w;
#pragma unroll
        for (int ni = 0; ni < 8; ++ni) {
            const half8 bf = *reinterpret_cast<const half8*>(bp + (size_t)ni * 16 * KPC + k0);
            acc[ni] = __builtin_amdgcn_mfma_f32_16x16x32_f16(af, bf, acc[ni], 0, 0, 0);
        }
    }

    // C/D layout: col = lane&15, row = quad*4 + g  [m89-verified]
#pragma unroll
    for (int ni = 0; ni < 8; ++ni)
#pragma unroll
        for (int g = 0; g < 4; ++g)
            out[(size_t)(m0 + quad * 4 + g) * 128 + ni * 16 + fr] = fmaxf(acc[ni][g], 0.f);
}

// ---------------------------------------------------------------------------
// Fallback path (only if assumptions violated): direct vector scatter.
// ---------------------------------------------------------------------------
__global__ void rwb_f32_kernel(const float* __restrict__ rel, const float* __restrict__ W,
                               const float* __restrict__ b, float* __restrict__ rwb, int R) {
    const int k = blockIdx.x;
    const int n = threadIdx.x;
    __shared__ float relk[128];
    relk[n] = rel[(size_t)k * 128 + n];
    __syncthreads();
    const float4* w4 = reinterpret_cast<const float4*>(W + (size_t)n * 128);
    const float4* r4 = reinterpret_cast<const float4*>(relk);
    float acc = 0.f;
#pragma unroll
    for (int i = 0; i < 32; ++i) {
        float4 a = r4[i], w = w4[i];
        acc += a.x * w.x + a.y * w.y + a.z * w.z + a.w * w.w;
    }
    rwb[(size_t)k * 128 + n] = acc + b[n];
}

__global__ void scatter_vec_kernel(const int* __restrict__ heads, const int* __restrict__ tails,
                                   const int* __restrict__ rels, const float* __restrict__ val,
                                   const float* __restrict__ rwb, float* __restrict__ out,
                                   long long nitems) {
    const long long i = (long long)blockIdx.x * blockDim.x + threadIdx.x;
    if (i >= nitems) return;
    const int e = (int)(i >> 5);
    const int c = (int)(i & 31) * 4;
    const float v = val[e];
    float4 rw = *reinterpret_cast<const float4*>(rwb + (size_t)rels[e] * 128 + c);
    float* pt = out + (size_t)tails[e] * 128 + c;
    float* ph = out + (size_t)heads[e] * 128 + c;
    unsafeAtomicAdd(pt + 0, v * rw.x); unsafeAtomicAdd(pt + 1, v * rw.y);
    unsafeAtomicAdd(pt + 2, v * rw.z); unsafeAtomicAdd(pt + 3, v * rw.w);
    unsafeAtomicAdd(ph + 0, v * rw.x); unsafeAtomicAdd(ph + 1, v * rw.y);
    unsafeAtomicAdd(ph + 2, v * rw.z); unsafeAtomicAdd(ph + 3, v * rw.w);
}

__global__ void relu_kernel(float* __restrict__ out, int n4) {
    const int i = blockIdx.x * blockDim.x + threadIdx.x;
    if (i >= n4) return;
    float4* p = reinterpret_cast<float4*>(out) + i;
    float4 v = *p;
    v.x = fmaxf(v.x, 0.f); v.y = fmaxf(v.y, 0.f);
    v.z = fmaxf(v.z, 0.f); v.w = fmaxf(v.w, 0.f);
    *p = v;
}

// ---------------------------------------------------------------------------
extern "C" void kernel_launch(void* const* d_in, const int* in_sizes, int n_in,
                              void* d_out, int out_size, void* d_ws, size_t ws_size,
                              hipStream_t stream) {
    // inputs: 0 local_entity [B*M], 1 heads [E], 2 tails [E], 3 rels [E],
    //         4 val [E], 5 rel_features [R*D], 6 W [D*D], 7 b [D]
    const int* heads = (const int*)d_in[1];
    const int* tails = (const int*)d_in[2];
    const int* rels  = (const int*)d_in[3];
    const float* val  = (const float*)d_in[4];
    const float* relf = (const float*)d_in[5];
    const float* W    = (const float*)d_in[6];
    const float* b    = (const float*)d_in[7];
    float* out = (float*)d_out;

    const int NUMENT = in_sizes[0];          // 16000
    const int E      = in_sizes[1];          // 2,000,000
    const int D      = in_sizes[7];          // 128
    const int R      = in_sizes[5] / D;      // 2000

    // slice_shift: smallest s with (NUMENT-1)>>s <= 7
    int slice_shift = 11;
    while (((NUMENT - 1) >> slice_shift) > 7) ++slice_shift;

    // workspace layout: [rwbT 512K][counters 256B][S 131MB]
    const size_t rwbT_bytes = (size_t)128 * KPC * sizeof(_Float16);     // 512 KB
    const size_t cnt_off    = (rwbT_bytes + 255) & ~(size_t)255;
    const size_t S_off      = cnt_off + 256;
    const size_t S_bytes    = (size_t)NUMENT * KPC * sizeof(float);     // ~131 MB
    const size_t total      = S_off + S_bytes;

    const bool fast = (D == 128) && (R <= KPC) && (NUMENT % 16 == 0) &&
                      (ws_size >= total);

    if (fast) {
        _Float16* rwbT = (_Float16*)d_ws;
        int* counters  = (int*)((char*)d_ws + cnt_off);
        float* S       = (float*)((char*)d_ws + S_off);

        const int chunk  = 4096;
        const int nchunk = (E + chunk - 1) / chunk;

        hipMemsetAsync((char*)d_ws + cnt_off, 0, 256 + S_bytes, stream);
        rwb_kernel<<<KPC, 128, 0, stream>>>(relf, W, b, rwbT, R);
        xcd_scatter_kernel<<<2048, 256, 0, stream>>>(heads, tails, rels, val,
                                                     S, counters, E, nchunk, chunk,
                                                     slice_shift);
        gemm16_kernel<<<NUMENT / 16, 64, 0, stream>>>(S, rwbT, out);
    } else {
        // fallback: accumulate directly into out
        float* rwb = (float*)d_ws;
        hipMemsetAsync(out, 0, (size_t)out_size * sizeof(float), stream);
        rwb_f32_kernel<<<R, 128, 0, stream>>>(relf, W, b, rwb, R);
        const long long items = (long long)E * 32;
        scatter_vec_kernel<<<(unsigned)((items + 255) / 256), 256, 0, stream>>>(
            heads, tails, rels, val, rwb, out, items);
        relu_kernel<<<(out_size / 4 + 255) / 256, 256, 0, stream>>>(out, out_size / 4);
    }
}